// Round 19
// baseline (74.442 us; speedup 1.0000x reference)
//
#include <hip/hip_runtime.h>
#include <math.h>

// All GEMM operands in MFMA-FRAGMENT-ORDER (zero-LDS zero-barrier GEMMs):
//   fragoff(m,k) of [M][768]: ((m>>4)*24 + (k>>5))*512 + ((m&15) + 16*((k&31)>>3))*8 + (k&7)
// Q/K/V keep the R6 fragment-order layouts.
// HEADS=12, DH=64.  Q pre-scaled by 0.125*log2(e) -> softmax in exp2 domain.
// R19: attn 4-way KV split: block = 32 q-rows, wave w owns KV quarter
// (256 keys); 1536 blocks = 6/CU = 24 waves/CU for latency hiding.
// 3-step LDS merge tree reusing 2 slots.

typedef __attribute__((ext_vector_type(8))) __bf16 bf16x8;
typedef __attribute__((ext_vector_type(4))) float f32x4;
typedef __attribute__((ext_vector_type(16))) float f32x16;
typedef unsigned short u16;
typedef unsigned int u32;

#define ZERO16 {0,0,0,0,0,0,0,0,0,0,0,0,0,0,0,0}

__device__ __forceinline__ u16 f2bf(float f) {
    union { float f; unsigned u; } v; v.f = f;
    unsigned r = v.u + 0x7FFF + ((v.u >> 16) & 1);   // RNE
    return (u16)(r >> 16);
}

__device__ __forceinline__ u32 cvtpk(float lo, float hi) {
    u32 r;
    asm("v_cvt_pk_bf16_f32 %0, %1, %2" : "=v"(r) : "v"(lo), "v"(hi));
    return r;
}
__device__ __forceinline__ float xhalf_max(float x) {
    float o = __shfl_xor(x, 32);
    return fmaxf(x, o);
}
__device__ __forceinline__ float xhalf_sum(float x) {
    float o = __shfl_xor(x, 32);
    return x + o;
}

__device__ __forceinline__ size_t fragoff(int m, int k) {
    return (((size_t)(m >> 4) * 24 + (k >> 5)) * 64 + (m & 15) + 16 * ((k & 31) >> 3)) * 8 + (k & 7);
}

// ---------------------------------------------------------------------------
// prep (R18 exact)
// ---------------------------------------------------------------------------
__global__ __launch_bounds__(256) void prep(const float* __restrict__ x,
                                            const float* __restrict__ w_qkv,
                                            const float* __restrict__ w_out,
                                            u16* __restrict__ xA,
                                            u16* __restrict__ wB,
                                            u16* __restrict__ wO) {
    const int bid = blockIdx.x;
    const int tid = threadIdx.x;
    if (bid < 1536) {
        __shared__ float Tx[32][65];
        const int mt = bid & 127;
        const int kt = bid >> 7;
        const int r0 = mt * 32, k0 = kt * 64;
#pragma unroll
        for (int p = 0; p < 2; ++p) {
            int idx = tid + p * 256;
            int row = idx >> 4, c4 = idx & 15;
            float4 v = *reinterpret_cast<const float4*>(&x[(size_t)(r0 + row) * 768 + k0 + c4 * 4]);
            *reinterpret_cast<float4*>(&Tx[row][c4 * 4]) = v;
        }
        __syncthreads();
        const int f = tid >> 6, l = tid & 63;
        const int fm = f & 1, fk = f >> 1;
        const int lm = l & 15, lkc = l >> 4;
        const int lrow = fm * 16 + lm;
        const int lcol = fk * 32 + lkc * 8;
        float v0 = Tx[lrow][lcol + 0], v1 = Tx[lrow][lcol + 1];
        float v2 = Tx[lrow][lcol + 2], v3 = Tx[lrow][lcol + 3];
        float v4 = Tx[lrow][lcol + 4], v5 = Tx[lrow][lcol + 5];
        float v6 = Tx[lrow][lcol + 6], v7 = Tx[lrow][lcol + 7];
        int4 ov;
        ov.x = (int)cvtpk(v0, v1); ov.y = (int)cvtpk(v2, v3);
        ov.z = (int)cvtpk(v4, v5); ov.w = (int)cvtpk(v6, v7);
        *reinterpret_cast<int4*>(xA + fragoff(r0 + lrow, k0 + lcol)) = ov;
        return;
    }
    __shared__ float T[64][65];
    const float* in;
    u16* out;
    int C, n0, k0;
    if (bid < 1968) {
        int r = bid - 1536;
        in = w_qkv; out = wB; C = 2304;
        n0 = (r % 36) * 64; k0 = (r / 36) * 64;
    } else {
        int r = bid - 1968;
        in = w_out; out = wO; C = 768;
        n0 = (r % 12) * 64; k0 = (r / 12) * 64;
    }
#pragma unroll
    for (int p = 0; p < 16; ++p) {
        int idx = tid + p * 256;
        int row = idx >> 6, col = idx & 63;
        T[row][col] = in[(size_t)(k0 + row) * C + n0 + col];
    }
    __syncthreads();
#pragma unroll
    for (int q = 0; q < 2; ++q) {
        int lin = tid + q * 256;
        int nl = lin >> 3, kc = lin & 7;
        float v0 = T[kc * 8 + 0][nl], v1 = T[kc * 8 + 1][nl];
        float v2 = T[kc * 8 + 2][nl], v3 = T[kc * 8 + 3][nl];
        float v4 = T[kc * 8 + 4][nl], v5 = T[kc * 8 + 5][nl];
        float v6 = T[kc * 8 + 6][nl], v7 = T[kc * 8 + 7][nl];
        int4 ov;
        ov.x = (int)cvtpk(v0, v1); ov.y = (int)cvtpk(v2, v3);
        ov.z = (int)cvtpk(v4, v5); ov.w = (int)cvtpk(v6, v7);
        *reinterpret_cast<int4*>(out + fragoff(n0 + nl, k0 + kc * 8)) = ov;
    }
}

// ---------------------------------------------------------------------------
// GEMM1 (R18/R17 exact)
// ---------------------------------------------------------------------------
__global__ __launch_bounds__(256) void gemm_qkv(const u16* __restrict__ xA,
                                                const u16* __restrict__ wB,
                                                u16* __restrict__ Qf,
                                                u16* __restrict__ Kf,
                                                u16* __restrict__ Vf) {
    __shared__ u16 tile[4][64 * 68];
    const int tid = threadIdx.x;
    const int lane = tid & 63;
    const int w = tid >> 6;
    const int wm = w >> 1, wn = w & 1;
    const int lr = lane & 15;
    const int lk = lane >> 4;
    const int xcd = blockIdx.x & 7;
    const int lid = blockIdx.x >> 3;
    const int row0 = ((xcd & 3) * 8 + (lid & 7)) * 128;
    const int col0 = ((xcd >> 2) * 9 + (lid >> 3)) * 128;
    const int R0 = row0 + wm * 64;
    const int C0 = col0 + wn * 64;
    const u16* aB = xA + (size_t)(R0 >> 4) * 24 * 512 + lane * 8;
    const u16* bB = wB + (size_t)(C0 >> 4) * 24 * 512 + lane * 8;

    f32x4 acc[4][4];
#pragma unroll
    for (int mi = 0; mi < 4; ++mi)
#pragma unroll
        for (int nj = 0; nj < 4; ++nj) acc[mi][nj] = (f32x4){0.f, 0.f, 0.f, 0.f};

    int4 ra[3][4], rb[3][4];
#define LOADF(S, T)                                                           \
    {                                                                         \
        _Pragma("unroll")                                                     \
        for (int mi = 0; mi < 4; ++mi) {                                      \
            ra[S][mi] = *reinterpret_cast<const int4*>(aB + ((size_t)mi * 24 + (T)) * 512); \
            rb[S][mi] = *reinterpret_cast<const int4*>(bB + ((size_t)mi * 24 + (T)) * 512); \
        }                                                                     \
    }
#define COMPUTEF(S)                                                           \
    {                                                                         \
        union { int4 i; bf16x8 v; } af[4], bf[4];                             \
        _Pragma("unroll")                                                     \
        for (int mi = 0; mi < 4; ++mi) { af[mi].i = ra[S][mi]; bf[mi].i = rb[S][mi]; } \
        __builtin_amdgcn_s_setprio(1);                                        \
        _Pragma("unroll")                                                     \
        for (int mi = 0; mi < 4; ++mi)                                        \
            _Pragma("unroll")                                                 \
            for (int nj = 0; nj < 4; ++nj)                                    \
                acc[mi][nj] = __builtin_amdgcn_mfma_f32_16x16x32_bf16(af[mi].v, bf[nj].v, acc[mi][nj], 0, 0, 0); \
        __builtin_amdgcn_s_setprio(0);                                        \
    }

    LOADF(0, 0);
    LOADF(1, 1);
    LOADF(2, 2);
#pragma unroll
    for (int t = 0; t < 24; ++t) {
        COMPUTEF(t % 3);
        if (t + 3 < 24) { LOADF(t % 3, t + 3); }
    }
#undef LOADF
#undef COMPUTEF

    const int which = col0 / 768;
    const int cb = col0 - which * 768;
    const int c0w = cb + wn * 64;
    const int b = R0 >> 10;
    const int n0 = R0 & 1023;
    const int h = c0w >> 6;
    const int bh = b * 12 + h;
    u16* tw = &tile[w][0];

    if (which != 2) {
        const float qs = (which == 0) ? 0.18033688f : 1.0f;   // 0.125*log2(e)
#pragma unroll
        for (int mi = 0; mi < 4; ++mi)
#pragma unroll
            for (int i = 0; i < 4; ++i)
#pragma unroll
                for (int nj = 0; nj < 4; ++nj)
                    tw[(mi * 16 + lk * 4 + i) * 68 + nj * 16 + lr] = f2bf(acc[mi][nj][i] * qs);
        u16* dst = (which == 0) ? Qf : Kf;
#pragma unroll
        for (int fb = 0; fb < 2; ++fb)
#pragma unroll
            for (int kt2 = 0; kt2 < 4; ++kt2) {
                int4 v = *reinterpret_cast<const int4*>(
                    &tw[(fb * 32 + (lane & 31)) * 68 + kt2 * 16 + (lane >> 5) * 8]);
                size_t off = ((((size_t)bh * 32 + (n0 >> 5) + fb) * 4 + kt2) * 2) * 256 + (size_t)lane * 8;
                *reinterpret_cast<int4*>(dst + off) = v;
            }
    } else {
#pragma unroll
        for (int mi = 0; mi < 4; ++mi)
#pragma unroll
            for (int i = 0; i < 4; ++i)
#pragma unroll
                for (int nj = 0; nj < 4; ++nj)
                    tw[(nj * 16 + lr) * 68 + mi * 16 + lk * 4 + i] = f2bf(acc[mi][nj][i]);
#pragma unroll
        for (int ks = 0; ks < 4; ++ks)
#pragma unroll
            for (int hia = 0; hia < 2; ++hia) {
                int4 v = *reinterpret_cast<const int4*>(&tw[lane * 68 + ks * 16 + hia * 8]);
                size_t off = ((((size_t)bh * 16 + (n0 >> 6)) * 4 + ks) * 2 + hia) * 512 + (size_t)lane * 8;
                *reinterpret_cast<int4*>(Vf + off) = v;
            }
    }
}

// ---------------------------------------------------------------------------
// Flash attention: 32 q-rows per block, wave w = KV quarter (256 keys,
// 4 iterations), 3-step LDS merge tree, fragment-major attnF write.
// ---------------------------------------------------------------------------
#define GETO(dt, r) ((dt) == 0 ? o0[r] : o1[r])

__global__ __launch_bounds__(256) void attn_mfma(const u16* __restrict__ Qf,
                                                 const u16* __restrict__ Kf,
                                                 const u16* __restrict__ Vf,
                                                 u16* __restrict__ attnF) {
    __shared__ float OtM[2][64][33];
    __shared__ float Lm[2][32], Ll[2][32];
    __shared__ u16 Os[32][72];

    const int tid = threadIdx.x;
    const int lane = tid & 63;
    const int w = tid >> 6;          // KV quarter 0..3
    const int l31 = lane & 31;
    const int hi = lane >> 5;

    // XCD swizzle: 1536 = 8 x 192; each XCD hosts 6 bh (192/32 q-blocks)
    const int bid = blockIdx.x;
    const int lin = (bid & 7) * 192 + (bid >> 3);
    const int qt2 = lin & 31;        // 32-row q block
    const int bh = lin >> 5;

    const u16* Qh = Qf + (size_t)bh * 65536;
    const u16* Kh = Kf + (size_t)bh * 65536;
    const u16* Vh = Vf + (size_t)bh * 65536;

    bf16x8 qf[4];
#pragma unroll
    for (int kt = 0; kt < 4; ++kt)
        qf[kt] = *reinterpret_cast<const bf16x8*>(
            Qh + (((size_t)qt2 * 4 + kt) * 2 + hi) * 256 + l31 * 8);

    f32x16 o0 = ZERO16, o1 = ZERO16;
    float m = -1e30f, l = 0.f;

    for (int it = 0; it < 4; ++it) {
        const int kb0 = it * 8 + w * 2;       // 32-key block
        const int kvb = it * 4 + w;           // 64-key block

        bf16x8 kf0[4], kf1[4];
#pragma unroll
        for (int kt = 0; kt < 4; ++kt) {
            kf0[kt] = *reinterpret_cast<const bf16x8*>(
                Kh + (((size_t)kb0 * 4 + kt) * 2 + hi) * 256 + l31 * 8);
            kf1[kt] = *reinterpret_cast<const bf16x8*>(
                Kh + (((size_t)(kb0 + 1) * 4 + kt) * 2 + hi) * 256 + l31 * 8);
        }
        bf16x8 vf0[4], vf1[4];
#pragma unroll
        for (int ks = 0; ks < 4; ++ks) {
            const u16* vb = Vh + (((size_t)kvb * 4 + ks) * 2 + hi) * 512;
            vf0[ks] = *reinterpret_cast<const bf16x8*>(vb + l31 * 8);
            vf1[ks] = *reinterpret_cast<const bf16x8*>(vb + (l31 + 32) * 8);
        }

        f32x16 s0 = ZERO16, s1 = ZERO16;
        __builtin_amdgcn_s_setprio(1);
#pragma unroll
        for (int kt = 0; kt < 4; ++kt) s0 = __builtin_amdgcn_mfma_f32_32x32x16_bf16(kf0[kt], qf[kt], s0, 0, 0, 0);
#pragma unroll
        for (int kt = 0; kt < 4; ++kt) s1 = __builtin_amdgcn_mfma_f32_32x32x16_bf16(kf1[kt], qf[kt], s1, 0, 0, 0);
        __builtin_amdgcn_s_setprio(0);

        float mx[8];
#pragma unroll
        for (int i = 0; i < 8; ++i)
            mx[i] = fmaxf(fmaxf(s0[2*i], s0[2*i+1]), fmaxf(s1[2*i], s1[2*i+1]));
        float pmax = fmaxf(fmaxf(fmaxf(mx[0], mx[1]), fmaxf(mx[2], mx[3])),
                           fmaxf(fmaxf(mx[4], mx[5]), fmaxf(mx[6], mx[7])));
        pmax = xhalf_max(pmax);

        if (!__all(pmax <= m + 8.f)) {
            float mn = fmaxf(m, pmax);
            float c = __builtin_amdgcn_exp2f(m - mn);
            m = mn; l *= c;
            o0 = o0 * c; o1 = o1 * c;
        }

#pragma unroll
        for (int r = 0; r < 16; ++r) s0[r] = __builtin_amdgcn_exp2f(s0[r] - m);
#pragma unroll
        for (int r = 0; r < 16; ++r) s1[r] = __builtin_amdgcn_exp2f(s1[r] - m);
        float sm[8];
#pragma unroll
        for (int i = 0; i < 8; ++i)
            sm[i] = (s0[2*i] + s0[2*i+1]) + (s1[2*i] + s1[2*i+1]);
        float tsum = ((sm[0]+sm[1]) + (sm[2]+sm[3])) + ((sm[4]+sm[5]) + (sm[6]+sm[7]));
        l += xhalf_sum(tsum);

        bf16x8 pb[4];
#define PACK_GROUP(S, G, OUT)                                           \
        {                                                               \
            u32 X0 = cvtpk(S[8*(G)+0], S[8*(G)+1]);                     \
            u32 X1 = cvtpk(S[8*(G)+2], S[8*(G)+3]);                     \
            u32 Y0 = cvtpk(S[8*(G)+4], S[8*(G)+5]);                     \
            u32 Y1 = cvtpk(S[8*(G)+6], S[8*(G)+7]);                     \
            asm("v_permlane32_swap_b32 %0, %1" : "+v"(X0), "+v"(Y0));   \
            asm("v_permlane32_swap_b32 %0, %1" : "+v"(X1), "+v"(Y1));   \
            union { u32 u[4]; bf16x8 v; } pk_;                          \
            pk_.u[0] = X0;                                              \
            pk_.u[1] = X1;                                              \
            pk_.u[2] = Y0;                                              \
            pk_.u[3] = Y1;                                              \
            OUT = pk_.v;                                                \
        }
        PACK_GROUP(s0, 0, pb[0]);
        PACK_GROUP(s0, 1, pb[1]);
        PACK_GROUP(s1, 0, pb[2]);
        PACK_GROUP(s1, 1, pb[3]);
#undef PACK_GROUP

        __builtin_amdgcn_s_setprio(1);
#pragma unroll
        for (int ks = 0; ks < 4; ++ks) {
            o0 = __builtin_amdgcn_mfma_f32_32x32x16_bf16(vf0[ks], pb[ks], o0, 0, 0, 0);
            o1 = __builtin_amdgcn_mfma_f32_32x32x16_bf16(vf1[ks], pb[ks], o1, 0, 0, 0);
        }
        __builtin_amdgcn_s_setprio(0);
    }

    // ---- 3-step merge tree: (w0<-w1, w2<-w3), then w0<-w2 ----
#define PUBLISH(SLOT)                                                         \
    {                                                                         \
        _Pragma("unroll")                                                     \
        for (int dt = 0; dt < 2; ++dt)                                        \
            _Pragma("unroll")                                                 \
            for (int r = 0; r < 16; ++r)                                      \
                OtM[SLOT][dt * 32 + (r & 3) + 8 * (r >> 2) + 4 * hi][l31] = GETO(dt, r); \
        Lm[SLOT][l31] = m;                                                    \
        Ll[SLOT][l31] = l;                                                    \
    }
#define MERGEIN(SLOT)                                                         \
    {                                                                         \
        float m2 = Lm[SLOT][l31], l2 = Ll[SLOT][l31];                         \
        float mn = fmaxf(m, m2);                                              \
        float a = __builtin_amdgcn_exp2f(m - mn);                             \
        float bsc = __builtin_amdgcn_exp2f(m2 - mn);                          \
        _Pragma("unroll")                                                     \
        for (int r = 0; r < 16; ++r) {                                        \
            int d = (r & 3) + 8 * (r >> 2) + 4 * hi;                          \
            o0[r] = o0[r] * a + OtM[SLOT][d][l31] * bsc;                      \
            o1[r] = o1[r] * a + OtM[SLOT][32 + d][l31] * bsc;                 \
        }                                                                     \
        l = l * a + l2 * bsc;                                                 \
        m = mn;                                                               \
    }

    if (w == 1) PUBLISH(0);
    if (w == 3) PUBLISH(1);
    __syncthreads();
    if (w == 0) MERGEIN(0);
    if (w == 2) MERGEIN(1);
    __syncthreads();
    if (w == 2) PUBLISH(1);
    __syncthreads();
    if (w == 0) {
        MERGEIN(1);
        float inv = 1.0f / l;
#pragma unroll
        for (int dt = 0; dt < 2; ++dt)
#pragma unroll
            for (int rq = 0; rq < 4; ++rq) {
                int d0 = dt * 32 + 8 * rq + 4 * hi;
                float v0 = GETO(dt, rq * 4 + 0) * inv;
                float v1 = GETO(dt, rq * 4 + 1) * inv;
                float v2 = GETO(dt, rq * 4 + 2) * inv;
                float v3 = GETO(dt, rq * 4 + 3) * inv;
                uint2 pr;
                pr.x = cvtpk(v0, v1);
                pr.y = cvtpk(v2, v3);
                *reinterpret_cast<uint2*>(&Os[l31][d0]) = pr;
            }
    }
#undef PUBLISH
#undef MERGEIN
    __syncthreads();

    // fragment-major write-out: 4 fragments (2 mt x 2 kt2), one int4/thread
    const int b = bh / 12, h = bh % 12;
    const int mbase = (b * 1024 + qt2 * 32) >> 4;
    {
        int f = tid >> 6;                 // 0..3
        int l_ = tid & 63;
        int mt = f >> 1, kt2 = f & 1;
        int token = mt * 16 + (l_ & 15);
        int d = kt2 * 32 + (l_ >> 4) * 8;
        int4 v = *reinterpret_cast<const int4*>(&Os[token][d]);
        size_t off = (((size_t)(mbase + mt) * 24 + (h * 2 + kt2)) * 64) * 8 + (size_t)l_ * 8;
        *reinterpret_cast<int4*>(attnF + off) = v;
    }
}

// ---------------------------------------------------------------------------
// GEMM2 (R18/R14 exact)
// ---------------------------------------------------------------------------
__global__ __launch_bounds__(256) void gemm_out(const u16* __restrict__ attnF,
                                                const u16* __restrict__ wO,
                                                const float* __restrict__ bias,
                                                float* __restrict__ out) {
    const int tid = threadIdx.x;
    const int lane = tid & 63;
    const int w = tid >> 6;
    const int wm = w >> 1, wn = w & 1;
    const int lr = lane & 15;
    const int lk = lane >> 4;
    const int xcd = blockIdx.x & 7;
    const int lid = blockIdx.x >> 3;
    const int row0 = (xcd * 4 + (lid & 3)) * 128;
    const int col0 = (lid >> 2) * 128;
    const int R0 = row0 + wm * 64;
    const int C0 = col0 + wn * 64;
    const u16* aB = attnF + (size_t)(R0 >> 4) * 24 * 512 + lane * 8;
    const u16* bB = wO + (size_t)(C0 >> 4) * 24 * 512 + lane * 8;

    f32x4 acc[4][4];
#pragma unroll
    for (int mi = 0; mi < 4; ++mi)
#pragma unroll
        for (int nj = 0; nj < 4; ++nj) acc[mi][nj] = (f32x4){0.f, 0.f, 0.f, 0.f};

    int4 ra[3][4], rb[3][4];
#define LOADF(S, T)                                                           \
    {                                                                         \
        _Pragma("unroll")                                                     \
        for (int mi = 0; mi < 4; ++mi) {                                      \
            ra[S][mi] = *reinterpret_cast<const int4*>(aB + ((size_t)mi * 24 + (T)) * 512); \
            rb[S][mi] = *reinterpret_cast<const int4*>(bB + ((size_t)mi * 24 + (T)) * 512); \
        }                                                                     \
    }
#define COMPUTEF(S)                                                           \
    {                                                                         \
        union { int4 i; bf16x8 v; } af[4], bf[4];                             \
        _Pragma("unroll")                                                     \
        for (int mi = 0; mi < 4; ++mi) { af[mi].i = ra[S][mi]; bf[mi].i = rb[S][mi]; } \
        __builtin_amdgcn_s_setprio(1);                                        \
        _Pragma("unroll")                                                     \
        for (int mi = 0; mi < 4; ++mi)                                        \
            _Pragma("unroll")                                                 \
            for (int nj = 0; nj < 4; ++nj)                                    \
                acc[mi][nj] = __builtin_amdgcn_mfma_f32_16x16x32_bf16(af[mi].v, bf[nj].v, acc[mi][nj], 0, 0, 0); \
        __builtin_amdgcn_s_setprio(0);                                        \
    }

    LOADF(0, 0);
    LOADF(1, 1);
    LOADF(2, 2);
#pragma unroll
    for (int t = 0; t < 24; ++t) {
        COMPUTEF(t % 3);
        if (t + 3 < 24) { LOADF(t % 3, t + 3); }
    }
#undef LOADF
#undef COMPUTEF

#pragma unroll
    for (int mi = 0; mi < 4; ++mi)
#pragma unroll
        for (int i = 0; i < 4; ++i) {
            int r = row0 + wm * 64 + mi * 16 + lk * 4 + i;
#pragma unroll
            for (int nj = 0; nj < 4; ++nj) {
                int c = col0 + wn * 64 + nj * 16 + lr;
                out[(size_t)r * 768 + c] = acc[mi][nj][i] + bias[c];
            }
        }
}

// ---------------------------------------------------------------------------
extern "C" void kernel_launch(void* const* d_in, const int* in_sizes, int n_in,
                              void* d_out, int out_size, void* d_ws, size_t ws_size,
                              hipStream_t stream) {
    const float* x     = (const float*)d_in[0];
    const float* w_qkv = (const float*)d_in[1];
    const float* w_out = (const float*)d_in[2];
    const float* b_out = (const float*)d_in[3];
    float* out = (float*)d_out;

    u16* ws = (u16*)d_ws;
    const size_t n_x = (size_t)4096 * 768;
    u16* xA     = ws;
    u16* wB     = xA + n_x;
    u16* wO     = wB + (size_t)2304 * 768;
    u16* Qfr    = wO + (size_t)768 * 768;
    u16* Kfr    = Qfr + n_x;
    u16* Vfr    = Kfr + n_x;
    u16* attnF  = Vfr + n_x;

    prep<<<2112, 256, 0, stream>>>(x, w_qkv, w_out, xA, wB, wO);
    gemm_qkv<<<576, 256, 0, stream>>>(xA, wB, Qfr, Kfr, Vfr);
    attn_mfma<<<1536, 256, 0, stream>>>(Qfr, Kfr, Vfr, attnF);
    gemm_out<<<192, 256, 0, stream>>>(attnF, wO, b_out, out);
}

// Round 20
// 70.654 us; speedup vs baseline: 1.0536x; 1.0536x over previous
//
#include <hip/hip_runtime.h>
#include <math.h>

// All GEMM operands in MFMA-FRAGMENT-ORDER (zero-LDS zero-barrier GEMMs):
//   fragoff(m,k) of [M][768]: ((m>>4)*24 + (k>>5))*512 + ((m&15) + 16*((k&31)>>3))*8 + (k&7)
// Q/K/V keep the R6 fragment-order layouts.
// HEADS=12, DH=64.  Q pre-scaled by 0.125*log2(e) -> softmax in exp2 domain.
// GEMMs: 128x128 block, 4 waves, zero-LDS main loop, depth-3 reg prefetch,
// coalesced LDS-repack epilogues (R17).
// attn: fragment-major attnF write + permlane32_swap pack (R18, best: 70.7us).

typedef __attribute__((ext_vector_type(8))) __bf16 bf16x8;
typedef __attribute__((ext_vector_type(4))) float f32x4;
typedef __attribute__((ext_vector_type(16))) float f32x16;
typedef unsigned short u16;
typedef unsigned int u32;

#define ZERO16 {0,0,0,0,0,0,0,0,0,0,0,0,0,0,0,0}

__device__ __forceinline__ u16 f2bf(float f) {
    union { float f; unsigned u; } v; v.f = f;
    unsigned r = v.u + 0x7FFF + ((v.u >> 16) & 1);   // RNE
    return (u16)(r >> 16);
}

__device__ __forceinline__ u32 cvtpk(float lo, float hi) {
    u32 r;
    asm("v_cvt_pk_bf16_f32 %0, %1, %2" : "=v"(r) : "v"(lo), "v"(hi));
    return r;
}
__device__ __forceinline__ float xhalf_max(float x) {
    float o = __shfl_xor(x, 32);
    return fmaxf(x, o);
}
__device__ __forceinline__ float xhalf_sum(float x) {
    float o = __shfl_xor(x, 32);
    return x + o;
}

__device__ __forceinline__ size_t fragoff(int m, int k) {
    return (((size_t)(m >> 4) * 24 + (k >> 5)) * 64 + (m & 15) + 16 * ((k & 31) >> 3)) * 8 + (k & 7);
}

// ---------------------------------------------------------------------------
// prep: blocks 0..1535: x -> xA frag-order;
//       1536..1967: w_qkv -> wB frag-order (64x64 tiles, int4 stores);
//       1968..2111: w_out -> wO frag-order.
// ---------------------------------------------------------------------------
__global__ __launch_bounds__(256) void prep(const float* __restrict__ x,
                                            const float* __restrict__ w_qkv,
                                            const float* __restrict__ w_out,
                                            u16* __restrict__ xA,
                                            u16* __restrict__ wB,
                                            u16* __restrict__ wO) {
    const int bid = blockIdx.x;
    const int tid = threadIdx.x;
    if (bid < 1536) {
        __shared__ float Tx[32][65];
        const int mt = bid & 127;
        const int kt = bid >> 7;
        const int r0 = mt * 32, k0 = kt * 64;
#pragma unroll
        for (int p = 0; p < 2; ++p) {
            int idx = tid + p * 256;
            int row = idx >> 4, c4 = idx & 15;
            float4 v = *reinterpret_cast<const float4*>(&x[(size_t)(r0 + row) * 768 + k0 + c4 * 4]);
            *reinterpret_cast<float4*>(&Tx[row][c4 * 4]) = v;
        }
        __syncthreads();
        const int f = tid >> 6, l = tid & 63;
        const int fm = f & 1, fk = f >> 1;
        const int lm = l & 15, lkc = l >> 4;
        const int lrow = fm * 16 + lm;
        const int lcol = fk * 32 + lkc * 8;
        float v0 = Tx[lrow][lcol + 0], v1 = Tx[lrow][lcol + 1];
        float v2 = Tx[lrow][lcol + 2], v3 = Tx[lrow][lcol + 3];
        float v4 = Tx[lrow][lcol + 4], v5 = Tx[lrow][lcol + 5];
        float v6 = Tx[lrow][lcol + 6], v7 = Tx[lrow][lcol + 7];
        int4 ov;
        ov.x = (int)cvtpk(v0, v1); ov.y = (int)cvtpk(v2, v3);
        ov.z = (int)cvtpk(v4, v5); ov.w = (int)cvtpk(v6, v7);
        *reinterpret_cast<int4*>(xA + fragoff(r0 + lrow, k0 + lcol)) = ov;
        return;
    }
    // weight transpose, 64x64 fp32 tile -> frag-order int4 stores
    __shared__ float T[64][65];
    const float* in;
    u16* out;
    int C, n0, k0;
    if (bid < 1968) {
        int r = bid - 1536;               // 432 blocks: 12 k-tiles x 36 n-tiles
        in = w_qkv; out = wB; C = 2304;
        n0 = (r % 36) * 64; k0 = (r / 36) * 64;
    } else {
        int r = bid - 1968;               // 144 blocks: 12 x 12
        in = w_out; out = wO; C = 768;
        n0 = (r % 12) * 64; k0 = (r / 12) * 64;
    }
#pragma unroll
    for (int p = 0; p < 16; ++p) {
        int idx = tid + p * 256;
        int row = idx >> 6, col = idx & 63;
        T[row][col] = in[(size_t)(k0 + row) * C + n0 + col];
    }
    __syncthreads();
#pragma unroll
    for (int q = 0; q < 2; ++q) {
        int lin = tid + q * 256;          // 0..511
        int nl = lin >> 3, kc = lin & 7;
        float v0 = T[kc * 8 + 0][nl], v1 = T[kc * 8 + 1][nl];
        float v2 = T[kc * 8 + 2][nl], v3 = T[kc * 8 + 3][nl];
        float v4 = T[kc * 8 + 4][nl], v5 = T[kc * 8 + 5][nl];
        float v6 = T[kc * 8 + 6][nl], v7 = T[kc * 8 + 7][nl];
        int4 ov;
        ov.x = (int)cvtpk(v0, v1); ov.y = (int)cvtpk(v2, v3);
        ov.z = (int)cvtpk(v4, v5); ov.w = (int)cvtpk(v6, v7);
        *reinterpret_cast<int4*>(out + fragoff(n0 + nl, k0 + kc * 8)) = ov;
    }
}

// ---------------------------------------------------------------------------
// GEMM1: qkv = xA @ wB (both fragment-order) -> Qf (scaled), Kf, Vf.
// 128x128 block, 4 waves, zero-LDS main loop, depth-3 reg prefetch,
// wave-private LDS repack epilogue.
// ---------------------------------------------------------------------------
__global__ __launch_bounds__(256) void gemm_qkv(const u16* __restrict__ xA,
                                                const u16* __restrict__ wB,
                                                u16* __restrict__ Qf,
                                                u16* __restrict__ Kf,
                                                u16* __restrict__ Vf) {
    __shared__ u16 tile[4][64 * 68];     // per-wave 64x68 (pad 4) repack buffer
    const int tid = threadIdx.x;
    const int lane = tid & 63;
    const int w = tid >> 6;
    const int wm = w >> 1, wn = w & 1;
    const int lr = lane & 15;
    const int lk = lane >> 4;
    const int xcd = blockIdx.x & 7;
    const int lid = blockIdx.x >> 3;                  // 0..71
    const int row0 = ((xcd & 3) * 8 + (lid & 7)) * 128;
    const int col0 = ((xcd >> 2) * 9 + (lid >> 3)) * 128;
    const int R0 = row0 + wm * 64;
    const int C0 = col0 + wn * 64;
    const u16* aB = xA + (size_t)(R0 >> 4) * 24 * 512 + lane * 8;
    const u16* bB = wB + (size_t)(C0 >> 4) * 24 * 512 + lane * 8;

    f32x4 acc[4][4];
#pragma unroll
    for (int mi = 0; mi < 4; ++mi)
#pragma unroll
        for (int nj = 0; nj < 4; ++nj) acc[mi][nj] = (f32x4){0.f, 0.f, 0.f, 0.f};

    int4 ra[3][4], rb[3][4];
#define LOADF(S, T)                                                           \
    {                                                                         \
        _Pragma("unroll")                                                     \
        for (int mi = 0; mi < 4; ++mi) {                                      \
            ra[S][mi] = *reinterpret_cast<const int4*>(aB + ((size_t)mi * 24 + (T)) * 512); \
            rb[S][mi] = *reinterpret_cast<const int4*>(bB + ((size_t)mi * 24 + (T)) * 512); \
        }                                                                     \
    }
#define COMPUTEF(S)                                                           \
    {                                                                         \
        union { int4 i; bf16x8 v; } af[4], bf[4];                             \
        _Pragma("unroll")                                                     \
        for (int mi = 0; mi < 4; ++mi) { af[mi].i = ra[S][mi]; bf[mi].i = rb[S][mi]; } \
        __builtin_amdgcn_s_setprio(1);                                        \
        _Pragma("unroll")                                                     \
        for (int mi = 0; mi < 4; ++mi)                                        \
            _Pragma("unroll")                                                 \
            for (int nj = 0; nj < 4; ++nj)                                    \
                acc[mi][nj] = __builtin_amdgcn_mfma_f32_16x16x32_bf16(af[mi].v, bf[nj].v, acc[mi][nj], 0, 0, 0); \
        __builtin_amdgcn_s_setprio(0);                                        \
    }

    LOADF(0, 0);
    LOADF(1, 1);
    LOADF(2, 2);
#pragma unroll
    for (int t = 0; t < 24; ++t) {
        COMPUTEF(t % 3);
        if (t + 3 < 24) { LOADF(t % 3, t + 3); }
    }
#undef LOADF
#undef COMPUTEF

    // ---- epilogue: wave-private LDS repack -> coalesced fragment stores ----
    const int which = col0 / 768;        // block-uniform
    const int cb = col0 - which * 768;
    const int c0w = cb + wn * 64;
    const int b = R0 >> 10;
    const int n0 = R0 & 1023;
    const int h = c0w >> 6;
    const int bh = b * 12 + h;
    u16* tw = &tile[w][0];

    if (which != 2) {
        const float qs = (which == 0) ? 0.18033688f : 1.0f;   // 0.125*log2(e)
#pragma unroll
        for (int mi = 0; mi < 4; ++mi)
#pragma unroll
            for (int i = 0; i < 4; ++i)
#pragma unroll
                for (int nj = 0; nj < 4; ++nj)
                    tw[(mi * 16 + lk * 4 + i) * 68 + nj * 16 + lr] = f2bf(acc[mi][nj][i] * qs);
        u16* dst = (which == 0) ? Qf : Kf;
#pragma unroll
        for (int fb = 0; fb < 2; ++fb)
#pragma unroll
            for (int kt2 = 0; kt2 < 4; ++kt2) {
                int4 v = *reinterpret_cast<const int4*>(
                    &tw[(fb * 32 + (lane & 31)) * 68 + kt2 * 16 + (lane >> 5) * 8]);
                size_t off = ((((size_t)bh * 32 + (n0 >> 5) + fb) * 4 + kt2) * 2) * 256 + (size_t)lane * 8;
                *reinterpret_cast<int4*>(dst + off) = v;
            }
    } else {
#pragma unroll
        for (int mi = 0; mi < 4; ++mi)
#pragma unroll
            for (int i = 0; i < 4; ++i)
#pragma unroll
                for (int nj = 0; nj < 4; ++nj)
                    tw[(nj * 16 + lr) * 68 + mi * 16 + lk * 4 + i] = f2bf(acc[mi][nj][i]);
#pragma unroll
        for (int ks = 0; ks < 4; ++ks)
#pragma unroll
            for (int hia = 0; hia < 2; ++hia) {
                int4 v = *reinterpret_cast<const int4*>(&tw[lane * 68 + ks * 16 + hia * 8]);
                size_t off = ((((size_t)bh * 16 + (n0 >> 6)) * 4 + ks) * 2 + hia) * 512 + (size_t)lane * 8;
                *reinterpret_cast<int4*>(Vf + off) = v;
            }
    }
}

// ---------------------------------------------------------------------------
// Flash attention: permlane32_swap pack + fragment-major coalesced attnF
// write (R18 exact).
// ---------------------------------------------------------------------------
#define GETO(dt, r) ((dt) == 0 ? o0[r] : o1[r])

__global__ __launch_bounds__(256) void attn_mfma(const u16* __restrict__ Qf,
                                                 const u16* __restrict__ Kf,
                                                 const u16* __restrict__ Vf,
                                                 u16* __restrict__ attnF) {
    __shared__ float OtM[2][64][33];
    __shared__ float Lm[2][32], Ll[2][32];
    __shared__ u16 Os[2][32][72];

    const int tid = threadIdx.x;
    const int lane = tid & 63;
    const int w = tid >> 6;
    const int qsub = w & 1;
    const int half = w >> 1;
    const int l31 = lane & 31;
    const int hi = lane >> 5;

    const int bid = blockIdx.x;
    const int lin = (bid & 7) * 96 + (bid >> 3);
    const int qt = lin & 15;
    const int bh = lin >> 4;

    const u16* Qh = Qf + (size_t)bh * 65536;
    const u16* Kh = Kf + (size_t)bh * 65536;
    const u16* Vh = Vf + (size_t)bh * 65536;

    bf16x8 qf[4];
#pragma unroll
    for (int kt = 0; kt < 4; ++kt)
        qf[kt] = *reinterpret_cast<const bf16x8*>(
            Qh + (((size_t)(qt * 2 + qsub) * 4 + kt) * 2 + hi) * 256 + l31 * 8);

    f32x16 o0 = ZERO16, o1 = ZERO16;
    float m = -1e30f, l = 0.f;

    for (int it = 0; it < 8; ++it) {
        const int kb0 = it * 4 + half * 2;
        const int kvb = it * 2 + half;

        bf16x8 kf0[4], kf1[4];
#pragma unroll
        for (int kt = 0; kt < 4; ++kt) {
            kf0[kt] = *reinterpret_cast<const bf16x8*>(
                Kh + (((size_t)kb0 * 4 + kt) * 2 + hi) * 256 + l31 * 8);
            kf1[kt] = *reinterpret_cast<const bf16x8*>(
                Kh + (((size_t)(kb0 + 1) * 4 + kt) * 2 + hi) * 256 + l31 * 8);
        }
        bf16x8 vf0[4], vf1[4];
#pragma unroll
        for (int ks = 0; ks < 4; ++ks) {
            const u16* vb = Vh + (((size_t)kvb * 4 + ks) * 2 + hi) * 512;
            vf0[ks] = *reinterpret_cast<const bf16x8*>(vb + l31 * 8);
            vf1[ks] = *reinterpret_cast<const bf16x8*>(vb + (l31 + 32) * 8);
        }

        f32x16 s0 = ZERO16, s1 = ZERO16;
        __builtin_amdgcn_s_setprio(1);
#pragma unroll
        for (int kt = 0; kt < 4; ++kt) s0 = __builtin_amdgcn_mfma_f32_32x32x16_bf16(kf0[kt], qf[kt], s0, 0, 0, 0);
#pragma unroll
        for (int kt = 0; kt < 4; ++kt) s1 = __builtin_amdgcn_mfma_f32_32x32x16_bf16(kf1[kt], qf[kt], s1, 0, 0, 0);
        __builtin_amdgcn_s_setprio(0);

        float mx[8];
#pragma unroll
        for (int i = 0; i < 8; ++i)
            mx[i] = fmaxf(fmaxf(s0[2*i], s0[2*i+1]), fmaxf(s1[2*i], s1[2*i+1]));
        float pmax = fmaxf(fmaxf(fmaxf(mx[0], mx[1]), fmaxf(mx[2], mx[3])),
                           fmaxf(fmaxf(mx[4], mx[5]), fmaxf(mx[6], mx[7])));
        pmax = xhalf_max(pmax);

        if (!__all(pmax <= m + 8.f)) {
            float mn = fmaxf(m, pmax);
            float c = __builtin_amdgcn_exp2f(m - mn);
            m = mn; l *= c;
            o0 = o0 * c; o1 = o1 * c;
        }

#pragma unroll
        for (int r = 0; r < 16; ++r) s0[r] = __builtin_amdgcn_exp2f(s0[r] - m);
#pragma unroll
        for (int r = 0; r < 16; ++r) s1[r] = __builtin_amdgcn_exp2f(s1[r] - m);
        float sm[8];
#pragma unroll
        for (int i = 0; i < 8; ++i)
            sm[i] = (s0[2*i] + s0[2*i+1]) + (s1[2*i] + s1[2*i+1]);
        float tsum = ((sm[0]+sm[1]) + (sm[2]+sm[3])) + ((sm[4]+sm[5]) + (sm[6]+sm[7]));
        l += xhalf_sum(tsum);

        bf16x8 pb[4];
#define PACK_GROUP(S, G, OUT)                                           \
        {                                                               \
            u32 X0 = cvtpk(S[8*(G)+0], S[8*(G)+1]);                     \
            u32 X1 = cvtpk(S[8*(G)+2], S[8*(G)+3]);                     \
            u32 Y0 = cvtpk(S[8*(G)+4], S[8*(G)+5]);                     \
            u32 Y1 = cvtpk(S[8*(G)+6], S[8*(G)+7]);                     \
            asm("v_permlane32_swap_b32 %0, %1" : "+v"(X0), "+v"(Y0));   \
            asm("v_permlane32_swap_b32 %0, %1" : "+v"(X1), "+v"(Y1));   \
            union { u32 u[4]; bf16x8 v; } pk_;                          \
            pk_.u[0] = X0;                                              \
            pk_.u[1] = X1;                                              \
            pk_.u[2] = Y0;                                              \
            pk_.u[3] = Y1;                                              \
            OUT = pk_.v;                                                \
        }
        PACK_GROUP(s0, 0, pb[0]);
        PACK_GROUP(s0, 1, pb[1]);
        PACK_GROUP(s1, 0, pb[2]);
        PACK_GROUP(s1, 1, pb[3]);
#undef PACK_GROUP

        __builtin_amdgcn_s_setprio(1);
#pragma unroll
        for (int ks = 0; ks < 4; ++ks) {
            o0 = __builtin_amdgcn_mfma_f32_32x32x16_bf16(vf0[ks], pb[ks], o0, 0, 0, 0);
            o1 = __builtin_amdgcn_mfma_f32_32x32x16_bf16(vf1[ks], pb[ks], o1, 0, 0, 0);
        }
        __builtin_amdgcn_s_setprio(0);
    }

    if (half == 1) {
#pragma unroll
        for (int dt = 0; dt < 2; ++dt)
#pragma unroll
            for (int r = 0; r < 16; ++r)
                OtM[qsub][dt * 32 + (r & 3) + 8 * (r >> 2) + 4 * hi][l31] = GETO(dt, r);
        Lm[qsub][l31] = m;
        Ll[qsub][l31] = l;
    }
    __syncthreads();
    if (half == 0) {
        float m2 = Lm[qsub][l31], l2 = Ll[qsub][l31];
        float mn = fmaxf(m, m2);
        float a = __builtin_amdgcn_exp2f(m - mn);
        float bsc = __builtin_amdgcn_exp2f(m2 - mn);
        float lm = l * a + l2 * bsc;
        float inv = 1.0f / lm;
        float av = a * inv, bv = bsc * inv;
#pragma unroll
        for (int dt = 0; dt < 2; ++dt)
#pragma unroll
            for (int rq = 0; rq < 4; ++rq) {
                int d0 = dt * 32 + 8 * rq + 4 * hi;
                float v0 = GETO(dt, rq * 4 + 0) * av + OtM[qsub][d0 + 0][l31] * bv;
                float v1 = GETO(dt, rq * 4 + 1) * av + OtM[qsub][d0 + 1][l31] * bv;
                float v2 = GETO(dt, rq * 4 + 2) * av + OtM[qsub][d0 + 2][l31] * bv;
                float v3 = GETO(dt, rq * 4 + 3) * av + OtM[qsub][d0 + 3][l31] * bv;
                uint2 pr;
                pr.x = cvtpk(v0, v1);
                pr.y = cvtpk(v2, v3);
                *reinterpret_cast<uint2*>(&Os[qsub][l31][d0]) = pr;
            }
    }
    __syncthreads();

    // fragment-major write-out: each 64-lane group writes one contiguous
    // 1KB fragment of attnF (base + lane*8).
    const int b = bh / 12, h = bh % 12;
    const int mbase = (b * 1024 + qt * 64) >> 4;      // 16-row fragment base
#pragma unroll
    for (int it2 = 0; it2 < 2; ++it2) {
        int idx = tid + it2 * 256;        // 0..511
        int f = idx >> 6;                 // fragment 0..7
        int l = idx & 63;
        int mt = f >> 1, kt2 = f & 1;
        int token = mt * 16 + (l & 15);
        int d = kt2 * 32 + (l >> 4) * 8;
        int4 v = *reinterpret_cast<const int4*>(&Os[token >> 5][token & 31][d]);
        size_t off = (((size_t)(mbase + mt) * 24 + (h * 2 + kt2)) * 64) * 8 + (size_t)l * 8;
        *reinterpret_cast<int4*>(attnF + off) = v;
    }
}

// ---------------------------------------------------------------------------
// GEMM2: out = attnF @ wO + b_out.  192 blocks = 8 XCD x (4x6).
// ---------------------------------------------------------------------------
__global__ __launch_bounds__(256) void gemm_out(const u16* __restrict__ attnF,
                                                const u16* __restrict__ wO,
                                                const float* __restrict__ bias,
                                                float* __restrict__ out) {
    const int tid = threadIdx.x;
    const int lane = tid & 63;
    const int w = tid >> 6;
    const int wm = w >> 1, wn = w & 1;
    const int lr = lane & 15;
    const int lk = lane >> 4;
    const int xcd = blockIdx.x & 7;
    const int lid = blockIdx.x >> 3;                  // 0..23
    const int row0 = (xcd * 4 + (lid & 3)) * 128;
    const int col0 = (lid >> 2) * 128;
    const int R0 = row0 + wm * 64;
    const int C0 = col0 + wn * 64;
    const u16* aB = attnF + (size_t)(R0 >> 4) * 24 * 512 + lane * 8;
    const u16* bB = wO + (size_t)(C0 >> 4) * 24 * 512 + lane * 8;

    f32x4 acc[4][4];
#pragma unroll
    for (int mi = 0; mi < 4; ++mi)
#pragma unroll
        for (int nj = 0; nj < 4; ++nj) acc[mi][nj] = (f32x4){0.f, 0.f, 0.f, 0.f};

    int4 ra[3][4], rb[3][4];
#define LOADF(S, T)                                                           \
    {                                                                         \
        _Pragma("unroll")                                                     \
        for (int mi = 0; mi < 4; ++mi) {                                      \
            ra[S][mi] = *reinterpret_cast<const int4*>(aB + ((size_t)mi * 24 + (T)) * 512); \
            rb[S][mi] = *reinterpret_cast<const int4*>(bB + ((size_t)mi * 24 + (T)) * 512); \
        }                                                                     \
    }
#define COMPUTEF(S)                                                           \
    {                                                                         \
        union { int4 i; bf16x8 v; } af[4], bf[4];                             \
        _Pragma("unroll")                                                     \
        for (int mi = 0; mi < 4; ++mi) { af[mi].i = ra[S][mi]; bf[mi].i = rb[S][mi]; } \
        __builtin_amdgcn_s_setprio(1);                                        \
        _Pragma("unroll")                                                     \
        for (int mi = 0; mi < 4; ++mi)                                        \
            _Pragma("unroll")                                                 \
            for (int nj = 0; nj < 4; ++nj)                                    \
                acc[mi][nj] = __builtin_amdgcn_mfma_f32_16x16x32_bf16(af[mi].v, bf[nj].v, acc[mi][nj], 0, 0, 0); \
        __builtin_amdgcn_s_setprio(0);                                        \
    }

    LOADF(0, 0);
    LOADF(1, 1);
    LOADF(2, 2);
#pragma unroll
    for (int t = 0; t < 24; ++t) {
        COMPUTEF(t % 3);
        if (t + 3 < 24) { LOADF(t % 3, t + 3); }
    }
#undef LOADF
#undef COMPUTEF

#pragma unroll
    for (int mi = 0; mi < 4; ++mi)
#pragma unroll
        for (int i = 0; i < 4; ++i) {
            int r = row0 + wm * 64 + mi * 16 + lk * 4 + i;
#pragma unroll
            for (int nj = 0; nj < 4; ++nj) {
                int c = col0 + wn * 64 + nj * 16 + lr;
                out[(size_t)r * 768 + c] = acc[mi][nj][i] + bias[c];
            }
        }
}

// ---------------------------------------------------------------------------
extern "C" void kernel_launch(void* const* d_in, const int* in_sizes, int n_in,
                              void* d_out, int out_size, void* d_ws, size_t ws_size,
                              hipStream_t stream) {
    const float* x     = (const float*)d_in[0];
    const float* w_qkv = (const float*)d_in[1];
    const float* w_out = (const float*)d_in[2];
    const float* b_out = (const float*)d_in[3];
    float* out = (float*)d_out;

    u16* ws = (u16*)d_ws;
    const size_t n_x = (size_t)4096 * 768;
    u16* xA     = ws;
    u16* wB     = xA + n_x;
    u16* wO     = wB + (size_t)2304 * 768;
    u16* Qfr    = wO + (size_t)768 * 768;
    u16* Kfr    = Qfr + n_x;
    u16* Vfr    = Kfr + n_x;
    u16* attnF  = Vfr + n_x;

    prep<<<2112, 256, 0, stream>>>(x, w_qkv, w_out, xA, wB, wO);
    gemm_qkv<<<576, 256, 0, stream>>>(xA, wB, Qfr, Kfr, Vfr);
    attn_mfma<<<768, 256, 0, stream>>>(Qfr, Kfr, Vfr, attnF);
    gemm_out<<<192, 256, 0, stream>>>(attnF, wO, b_out, out);
}